// Round 7
// baseline (507.364 us; speedup 1.0000x reference)
//
#include <hip/hip_runtime.h>
#include <hip/hip_cooperative_groups.h>

namespace cg = cooperative_groups;

// out = dequant( int8_gemm( quant(x, in_scale), quant(w, absmax/127) ) + b_q )
// M = 8192, K = 1600, N = 6400.
// R12: (1) cooperative fused prep. quantx/wmax/quantw were 3 launches with w
// read twice (absmax is a global dep). Now ONE hipLaunchCooperativeKernel:
//   phase1: quantx grid-stride + per-block w-absmax -> partials[block]
//   grid.sync()
//   phase2: all blocks reduce partials (4KB, L2-hit) -> wscale; quantw tiles.
// No atomics, no init pass (every partial written before sync). Saves 2
// launches + makes phase-2 w re-read L2/L3-hot.
// (2) T5 s_setprio(1) around gemm MFMA cluster: 3 desync'd blocks/CU give
// wave role diversity (stage vs mfma) for the CU scheduler to arbitrate.
// R11 lesson: SQ_LDS_BANK_CONFLICT 1.024e7 is invariant to read-swizzle
// (= 4 cyc/wave-b128, m134's intrinsic 12-vs-8 cost) -- not a fixable alias.
// Kept: R10 32x32x32 MFMA; R9 nt stores (FETCH 235->55MB); R8 3 blocks/CU;
// R7 3-buf counted-vmcnt pipeline; R6 XOR chunk swizzle; R5 XCD swizzle.

#define M_DIM 8192
#define K_DIM 1600
#define N_DIM 6400
#define QMAXF 127.0f

typedef __attribute__((ext_vector_type(4))) int int4v;
typedef __attribute__((ext_vector_type(16))) int int16v;

// ---------------- ws layout ----------------
// [0, 4096)         : partials f32[1024] (per-block |w| max; written pre-sync)
// [4096, 4100)      : gmax f32 (global |w| max, written by block 0 phase 2)
// [4352, +M*K)      : x_q  int8, row-major [M][K]
// [.. , +N*K)       : wT_q int8, row-major [N][K]  (transposed weight)

__device__ __forceinline__ void load_lds16(const void* gptr, void* lptr) {
    __builtin_amdgcn_global_load_lds((__attribute__((address_space(1))) void*)gptr,
                                     (__attribute__((address_space(3))) void*)lptr,
                                     16, 0, 0);
}

// ---- fused prep: quantx + absmax(w) partials | grid.sync | reduce + quantw ----
__global__ __launch_bounds__(256, 4) void prep_kernel(
        const float* __restrict__ x, signed char* __restrict__ xq,
        const float* __restrict__ in_scale_p,
        const float* __restrict__ w, signed char* __restrict__ wT,
        float* __restrict__ partials, float* __restrict__ gmax_p) {
    __shared__ signed char tile[64 * 80];  // quantw transpose tile (phase 2)
    __shared__ float smax[4];

    const int tid     = threadIdx.x;
    const int gtid    = blockIdx.x * 256 + tid;
    const int gstride = gridDim.x * 256;

    // ---- phase 1a: quantize x -> int8, 64B loads / 16B stores ----
    const float s = *in_scale_p;
    const float4* x4 = (const float4*)x;
    for (int i = gtid; i < M_DIM * K_DIM / 16; i += gstride) {
        signed char tmp[16];
#pragma unroll
        for (int j = 0; j < 4; ++j) {
            float4 v = x4[(size_t)i * 4 + j];
            tmp[j * 4 + 0] = (signed char)fminf(fmaxf(rintf(v.x / s), -128.0f), 127.0f);
            tmp[j * 4 + 1] = (signed char)fminf(fmaxf(rintf(v.y / s), -128.0f), 127.0f);
            tmp[j * 4 + 2] = (signed char)fminf(fmaxf(rintf(v.z / s), -128.0f), 127.0f);
            tmp[j * 4 + 3] = (signed char)fminf(fmaxf(rintf(v.w / s), -128.0f), 127.0f);
        }
        *(int4v*)&xq[(size_t)i * 16] = *(const int4v*)tmp;
    }

    // ---- phase 1b: per-block partial absmax(w) -> partials[block] ----
    const float4* w4 = (const float4*)w;
    float m = 0.0f;
    for (int i = gtid; i < K_DIM * N_DIM / 4; i += gstride) {
        float4 v = w4[i];
        m = fmaxf(m, fmaxf(fmaxf(fabsf(v.x), fabsf(v.y)),
                           fmaxf(fabsf(v.z), fabsf(v.w))));
    }
#pragma unroll
    for (int off = 32; off > 0; off >>= 1)
        m = fmaxf(m, __shfl_down(m, off, 64));
    if ((tid & 63) == 0) smax[tid >> 6] = m;
    __syncthreads();
    if (tid == 0)
        partials[blockIdx.x] = fmaxf(fmaxf(smax[0], smax[1]),
                                     fmaxf(smax[2], smax[3]));

    cg::this_grid().sync();

    // ---- phase 2a: every block reduces partials (4KB, L2-hit) -> gmax ----
    float mm = 0.0f;
    for (int j = tid; j < (int)gridDim.x; j += 256) mm = fmaxf(mm, partials[j]);
#pragma unroll
    for (int off = 32; off > 0; off >>= 1)
        mm = fmaxf(mm, __shfl_down(mm, off, 64));
    __syncthreads();                       // smax reuse safety
    if ((tid & 63) == 0) smax[tid >> 6] = mm;
    __syncthreads();
    const float gmax = fmaxf(fmaxf(smax[0], smax[1]), fmaxf(smax[2], smax[3]));
    if (blockIdx.x == 0 && tid == 0) *gmax_p = gmax;  // for gemm epilogue
    const float wscale = gmax / QMAXF;

    // ---- phase 2b: quantize + transpose w, grid-stride over 64x64 tiles ----
    const int tiles_n = N_DIM / 64;              // 100
    const int n_tiles = tiles_n * (K_DIM / 64);  // 2500
    const int nn = tid & 63;
    const int kb = tid >> 6;  // 0..3
    for (int t = blockIdx.x; t < n_tiles; t += gridDim.x) {
        const int n0 = (t % tiles_n) * 64;
        const int k0 = (t / tiles_n) * 64;
        __syncthreads();  // previous-iteration tile reads done before overwrite
#pragma unroll
        for (int p = 0; p < 16; ++p) {
            const int kk = p * 4 + kb;
            float v = w[(size_t)(k0 + kk) * N_DIM + n0 + nn];  // coalesced along n
            float q = fminf(fmaxf(rintf(v / wscale), -128.0f), 127.0f);
            tile[nn * 80 + kk] = (signed char)q;               // transposed in LDS
        }
        __syncthreads();
        const int n_loc = tid >> 2;
        const int kq = tid & 3;
        int4v val = *(const int4v*)&tile[n_loc * 80 + kq * 16];
        *(int4v*)&wT[(size_t)(n0 + n_loc) * K_DIM + k0 + kq * 16] = val;
    }
}

// --- int8 GEMM, 128x128 tile, BK=64, 32x32x32 MFMA, 3-buf counted-vmcnt ---
__global__ __launch_bounds__(256, 3) void gemm_i8_kernel(
        const signed char* __restrict__ xq, const signed char* __restrict__ wTq,
        const float* __restrict__ bias, const float* __restrict__ gmax_p,
        const float* __restrict__ in_scale_p, const float* __restrict__ out_scale_p,
        float* __restrict__ out) {
    __shared__ signed char A_lds[3][128 * 64];  // 3 x 8 KB  [m][k-chunk swizzled]
    __shared__ signed char B_lds[3][128 * 64];  // 3 x 8 KB  [n][k-chunk swizzled]

    const int tid   = threadIdx.x;
    const int wave  = tid >> 6;
    const int lane  = tid & 63;
    const int l31   = lane & 31;
    const int hi    = lane >> 5;          // k-half within 32-wide lane group
    const int waveM = wave >> 1;
    const int waveN = wave & 1;

    // XCD-aware swizzle: round-robin dispatch puts gid%8 on XCD gid&7.
    // XCD j owns m-blocks [8j, 8j+8); within an XCD: n outer, m inner.
    const int gid   = blockIdx.x;           // 0..3199
    const int xcd   = gid & 7;
    const int idx   = gid >> 3;             // 0..399
    const int n_blk = idx >> 3;             // 0..49
    const int m_blk = (xcd << 3) | (idx & 7);  // 0..63

    const int blockN0 = n_blk * 128;
    const int blockM0 = m_blk * 128;

    const signed char* Ag = xq  + (size_t)blockM0 * K_DIM;
    const signed char* Bg = wTq + (size_t)blockN0 * K_DIM;

    // Staging: LDS dest linear (global_load_lds requirement); XOR swizzle on the
    // GLOBAL chunk: LDS[row][c] = G[row][c ^ swz(row)],
    //   swz(row) = ((row>>1) ^ (row>>3)) & 3.
    const int srow = wave * 16 + (lane >> 2);
    const int sswz = (((lane >> 3) & 3) ^ ((2 * wave + (lane >> 5)) & 3));
    const int scol = (((lane & 3) ^ sswz) * 16);

    int16v acc[2][2];
#pragma unroll
    for (int mi = 0; mi < 2; ++mi)
#pragma unroll
        for (int ni = 0; ni < 2; ++ni)
#pragma unroll
            for (int r = 0; r < 16; ++r) acc[mi][ni][r] = 0;

    // Fragment reads: G[row][2ks+hi] = LDS[row][(2ks+hi)^swz(row)],
    // swz(row) = ((l31>>1) ^ (l31>>3)) & 3 (base/ti terms vanish mod 4).
    const int rswz = ((l31 >> 1) ^ (l31 >> 3)) & 3;

    const int NT = K_DIM / 64;  // 25 K-tiles

    // stage K-tile kt into LDS buffer sb (4 global_load_lds / thread)
    auto STAGE = [&](int sb, int kt) {
        const int kof = kt * 64;
#pragma unroll
        for (int t = 0; t < 2; ++t) {
            const int r = t * 64 + srow;
            load_lds16(Ag + (size_t)r * K_DIM + kof + scol,
                       &A_lds[sb][(t * 64 + wave * 16) * 64]);
            load_lds16(Bg + (size_t)r * K_DIM + kof + scol,
                       &B_lds[sb][(t * 64 + wave * 16) * 64]);
        }
    };

    auto COMPUTE = [&](int cb) {
        int4v a[2][2], b[2][2];  // [ks][tile]
#pragma unroll
        for (int ks = 0; ks < 2; ++ks)
#pragma unroll
            for (int ti = 0; ti < 2; ++ti) {
                const int ch = ((((ks << 1) | hi) ^ rswz) << 4);
                a[ks][ti] = *(const int4v*)
                    &A_lds[cb][(waveM * 64 + ti * 32 + l31) * 64 + ch];
                b[ks][ti] = *(const int4v*)
                    &B_lds[cb][(waveN * 64 + ti * 32 + l31) * 64 + ch];
            }
        __builtin_amdgcn_s_setprio(1);   // T5: favor MFMA-issuing wave
#pragma unroll
        for (int ks = 0; ks < 2; ++ks)
#pragma unroll
            for (int mi = 0; mi < 2; ++mi)
#pragma unroll
                for (int ni = 0; ni < 2; ++ni)
                    acc[mi][ni] = __builtin_amdgcn_mfma_i32_32x32x32_i8(
                        a[ks][mi], b[ks][ni], acc[mi][ni], 0, 0, 0);
        __builtin_amdgcn_s_setprio(0);
    };

    // ---- prologue: tiles 0,1 in flight ----
    STAGE(0, 0);
    STAGE(1, 1);

    // ---- main loop: steady-state 12 outstanding after STAGE; vmcnt(8)
    // completes tile t only -- t+1/t+2 loads stay in flight across barriers.
    int cb = 0;  // t % 3
    for (int t = 0; t < NT - 2; ++t) {
        const int sb = (cb == 0) ? 2 : cb - 1;  // (t+2) % 3
        STAGE(sb, t + 2);
        asm volatile("s_waitcnt vmcnt(8)" ::: "memory");
        __builtin_amdgcn_s_barrier();
        __builtin_amdgcn_sched_barrier(0);   // keep ds_reads below the barrier
        COMPUTE(cb);
        asm volatile("s_waitcnt lgkmcnt(0)" ::: "memory");
        __builtin_amdgcn_sched_barrier(0);   // keep MFMAs/reads above exit barrier
        __builtin_amdgcn_s_barrier();
        cb = (cb == 2) ? 0 : cb + 1;
    }

    // ---- tail: tile NT-2 (4 newer loads in flight), then NT-1 ----
    asm volatile("s_waitcnt vmcnt(4)" ::: "memory");
    __builtin_amdgcn_s_barrier();
    __builtin_amdgcn_sched_barrier(0);
    COMPUTE(cb);
    cb = (cb == 2) ? 0 : cb + 1;

    asm volatile("s_waitcnt vmcnt(0)" ::: "memory");
    __builtin_amdgcn_s_barrier();
    __builtin_amdgcn_sched_barrier(0);
    COMPUTE(cb);

    // epilogue: + b_q, rescale, rint, clip, dequant.
    // 32x32 C/D: col = lane&31 (N), row_m = (reg&3) + 8*(reg>>2) + 4*hi.
    // Nontemporal stores: write-once stream must not evict A/B from L2/L3.
    const float s_in  = *in_scale_p;
    const float s_out = *out_scale_p;
    const float wscale = *gmax_p / QMAXF;
    const float bias_scale = s_in * wscale;
    const float ratio = bias_scale / s_out;

#pragma unroll
    for (int ni = 0; ni < 2; ++ni) {
        const int col = blockN0 + waveN * 64 + ni * 32 + l31;
        const int bq = (int)rintf(bias[col] / bias_scale);
#pragma unroll
        for (int mi = 0; mi < 2; ++mi) {
#pragma unroll
            for (int reg = 0; reg < 16; ++reg) {
                const int row = blockM0 + waveM * 64 + mi * 32 +
                                (reg & 3) + 8 * (reg >> 2) + 4 * hi;
                const int av = acc[mi][ni][reg] + bq;
                float f = rintf((float)av * ratio);
                f = fminf(fmaxf(f, -128.0f), 127.0f);
                __builtin_nontemporal_store(f * s_out, &out[(size_t)row * N_DIM + col]);
            }
        }
    }
}

extern "C" void kernel_launch(void* const* d_in, const int* in_sizes, int n_in,
                              void* d_out, int out_size, void* d_ws, size_t ws_size,
                              hipStream_t stream) {
    const float* x         = (const float*)d_in[0];
    const float* w         = (const float*)d_in[1];
    const float* bias      = (const float*)d_in[2];
    const float* in_scale  = (const float*)d_in[3];
    const float* out_scale = (const float*)d_in[4];
    float* out = (float*)d_out;

    unsigned char* ws = (unsigned char*)d_ws;
    float* partials = (float*)ws;                       // [1024] f32, 4KB
    float* gmax_p   = (float*)(ws + 4096);              // global |w| max
    signed char* xq  = (signed char*)(ws + 4352);
    signed char* wTq = xq + (size_t)M_DIM * K_DIM;

    // One cooperative prep launch: grid 1024 = 4 blocks/CU (co-resident),
    // no memset/atomics needed (partials all written before grid.sync).
    void* args[] = {(void*)&x, (void*)&xq, (void*)&in_scale, (void*)&w,
                    (void*)&wTq, (void*)&partials, (void*)&gmax_p};
    hipLaunchCooperativeKernel((const void*)prep_kernel, dim3(1024), dim3(256),
                               args, 0, stream);

    gemm_i8_kernel<<<3200, 256, 0, stream>>>(xq, wTq, bias, gmax_p,
                                             in_scale, out_scale, out);
}

// Round 8
// 385.662 us; speedup vs baseline: 1.3156x; 1.3156x over previous
//
#include <hip/hip_runtime.h>

// out = dequant( int8_gemm( quant(x, in_scale), quant(w, absmax/127) ) + b_q )
// M = 8192, K = 1600, N = 6400.
// R13: revert R12's cooperative fusion (grid.sync on 8 non-coherent XCDs =
// device-scope L2 flush + coop-dispatch throttle: prep ran 147us @ 620GB/s,
// total 507us). Replace with dependency-safe fusion, NO grid sync:
//   kernel A: quantx (grid-stride) + per-block w-absmax -> partials[block]
//             (independent work; plain stores, no atomics, no memset)
//   kernel B: quantw; each block reduces partials (8KB, L2-hot) -> wscale;
//             block(0,0) writes gmax for the gemm epilogue (stream order).
// Saves one launch + merges two BW-bound passes. Gemm = exact R11 (setprio
// dropped: R12 replay showed it ~3us slower; m190 precedent negative).
// R11 lesson kept: SQ_LDS_BANK_CONFLICT 1.024e7 is swizzle-invariant
// (b128 intrinsic cost, m134) -- not chaseable.
// Kept: R10 32x32x32 MFMA + wide quantx; R9 nt stores (FETCH 235->55MB);
// R8 3 blocks/CU; R7 3-buf counted-vmcnt; R6 XOR chunk swizzle; R5 XCD swizzle.

#define M_DIM 8192
#define K_DIM 1600
#define N_DIM 6400
#define QMAXF 127.0f
#define PREP_GRID 2048

typedef __attribute__((ext_vector_type(4))) int int4v;
typedef __attribute__((ext_vector_type(16))) int int16v;

// ---------------- ws layout ----------------
// [0, 8192)         : partials f32[2048] (per-block |w| max, all written by A)
// [8192, 8196)      : gmax f32 (written by quantw block (0,0))
// [8448, +M*K)      : x_q  int8, row-major [M][K]
// [.. , +N*K)       : wT_q int8, row-major [N][K]  (transposed weight)

__device__ __forceinline__ void load_lds16(const void* gptr, void* lptr) {
    __builtin_amdgcn_global_load_lds((__attribute__((address_space(1))) void*)gptr,
                                     (__attribute__((address_space(3))) void*)lptr,
                                     16, 0, 0);
}

// ---- A: quantize x -> int8 [M][K]  +  per-block absmax(w) -> partials ----
__global__ __launch_bounds__(256) void quantx_wmax_kernel(
        const float* __restrict__ x, signed char* __restrict__ xq,
        const float* __restrict__ in_scale_p,
        const float* __restrict__ w, float* __restrict__ partials,
        int nx16, int nw4) {
    __shared__ float smax[4];
    const int tid     = threadIdx.x;
    const int gtid    = blockIdx.x * 256 + tid;
    const int gstride = gridDim.x * 256;

    // quantize x: 64B loads / 16B stores per iteration
    const float s = *in_scale_p;
    const float4* x4 = (const float4*)x;
    for (int i = gtid; i < nx16; i += gstride) {
        signed char tmp[16];
#pragma unroll
        for (int j = 0; j < 4; ++j) {
            float4 v = x4[(size_t)i * 4 + j];
            tmp[j * 4 + 0] = (signed char)fminf(fmaxf(rintf(v.x / s), -128.0f), 127.0f);
            tmp[j * 4 + 1] = (signed char)fminf(fmaxf(rintf(v.y / s), -128.0f), 127.0f);
            tmp[j * 4 + 2] = (signed char)fminf(fmaxf(rintf(v.z / s), -128.0f), 127.0f);
            tmp[j * 4 + 3] = (signed char)fminf(fmaxf(rintf(v.w / s), -128.0f), 127.0f);
        }
        *(int4v*)&xq[(size_t)i * 16] = *(const int4v*)tmp;
    }

    // absmax(w): wave reduce -> LDS -> one plain store per block (no atomics)
    const float4* w4 = (const float4*)w;
    float m = 0.0f;
    for (int i = gtid; i < nw4; i += gstride) {
        float4 v = w4[i];
        m = fmaxf(m, fmaxf(fmaxf(fabsf(v.x), fabsf(v.y)),
                           fmaxf(fabsf(v.z), fabsf(v.w))));
    }
#pragma unroll
    for (int off = 32; off > 0; off >>= 1)
        m = fmaxf(m, __shfl_down(m, off, 64));
    if ((tid & 63) == 0) smax[tid >> 6] = m;
    __syncthreads();
    if (tid == 0)
        partials[blockIdx.x] = fmaxf(fmaxf(smax[0], smax[1]),
                                     fmaxf(smax[2], smax[3]));
}

// ---- B: reduce partials -> wscale; quantize + transpose w -> int8 [N][K] ----
__global__ void quantw_kernel(const float* __restrict__ w, signed char* __restrict__ wT,
                              const float* __restrict__ partials,
                              float* __restrict__ gmax_p, int nparts) {
    __shared__ signed char tile[64 * 80];  // [n][k], stride 80 keeps 16B alignment
    __shared__ float smax[4];

    const int tid = threadIdx.x;

    // per-block reduce of partials (8KB, L2-hot after kernel A)
    float mm = 0.0f;
    for (int j = tid; j < nparts; j += 256) mm = fmaxf(mm, partials[j]);
#pragma unroll
    for (int off = 32; off > 0; off >>= 1)
        mm = fmaxf(mm, __shfl_down(mm, off, 64));
    if ((tid & 63) == 0) smax[tid >> 6] = mm;
    __syncthreads();
    const float gmax = fmaxf(fmaxf(smax[0], smax[1]), fmaxf(smax[2], smax[3]));
    if (blockIdx.x == 0 && blockIdx.y == 0 && tid == 0) *gmax_p = gmax;
    const float wscale = gmax / QMAXF;

    const int n0 = blockIdx.x * 64;
    const int k0 = blockIdx.y * 64;
    const int nn = tid & 63;
    const int kb = tid >> 6;  // 0..3
#pragma unroll
    for (int p = 0; p < 16; ++p) {
        const int kk = p * 4 + kb;
        float v = w[(size_t)(k0 + kk) * N_DIM + n0 + nn];  // coalesced along n
        float q = fminf(fmaxf(rintf(v / wscale), -128.0f), 127.0f);
        tile[nn * 80 + kk] = (signed char)q;               // transposed in LDS
    }
    __syncthreads();
    const int n_loc = tid >> 2;
    const int kq = tid & 3;
    int4v val = *(const int4v*)&tile[n_loc * 80 + kq * 16];
    *(int4v*)&wT[(size_t)(n0 + n_loc) * K_DIM + k0 + kq * 16] = val;
}

// --- int8 GEMM, 128x128 tile, BK=64, 32x32x32 MFMA, 3-buf counted-vmcnt ---
__global__ __launch_bounds__(256, 3) void gemm_i8_kernel(
        const signed char* __restrict__ xq, const signed char* __restrict__ wTq,
        const float* __restrict__ bias, const float* __restrict__ gmax_p,
        const float* __restrict__ in_scale_p, const float* __restrict__ out_scale_p,
        float* __restrict__ out) {
    __shared__ signed char A_lds[3][128 * 64];  // 3 x 8 KB  [m][k-chunk swizzled]
    __shared__ signed char B_lds[3][128 * 64];  // 3 x 8 KB  [n][k-chunk swizzled]

    const int tid   = threadIdx.x;
    const int wave  = tid >> 6;
    const int lane  = tid & 63;
    const int l31   = lane & 31;
    const int hi    = lane >> 5;          // k-half within 32-wide lane group
    const int waveM = wave >> 1;
    const int waveN = wave & 1;

    // XCD-aware swizzle: round-robin dispatch puts gid%8 on XCD gid&7.
    // XCD j owns m-blocks [8j, 8j+8); within an XCD: n outer, m inner.
    const int gid   = blockIdx.x;           // 0..3199
    const int xcd   = gid & 7;
    const int idx   = gid >> 3;             // 0..399
    const int n_blk = idx >> 3;             // 0..49
    const int m_blk = (xcd << 3) | (idx & 7);  // 0..63

    const int blockN0 = n_blk * 128;
    const int blockM0 = m_blk * 128;

    const signed char* Ag = xq  + (size_t)blockM0 * K_DIM;
    const signed char* Bg = wTq + (size_t)blockN0 * K_DIM;

    // Staging: LDS dest linear (global_load_lds requirement); XOR swizzle on the
    // GLOBAL chunk: LDS[row][c] = G[row][c ^ swz(row)],
    //   swz(row) = ((row>>1) ^ (row>>3)) & 3.
    const int srow = wave * 16 + (lane >> 2);
    const int sswz = (((lane >> 3) & 3) ^ ((2 * wave + (lane >> 5)) & 3));
    const int scol = (((lane & 3) ^ sswz) * 16);

    int16v acc[2][2];
#pragma unroll
    for (int mi = 0; mi < 2; ++mi)
#pragma unroll
        for (int ni = 0; ni < 2; ++ni)
#pragma unroll
            for (int r = 0; r < 16; ++r) acc[mi][ni][r] = 0;

    // Fragment reads: G[row][2ks+hi] = LDS[row][(2ks+hi)^swz(row)],
    // swz(row) = ((l31>>1) ^ (l31>>3)) & 3 (base/ti terms vanish mod 4).
    const int rswz = ((l31 >> 1) ^ (l31 >> 3)) & 3;

    const int NT = K_DIM / 64;  // 25 K-tiles

    // stage K-tile kt into LDS buffer sb (4 global_load_lds / thread)
    auto STAGE = [&](int sb, int kt) {
        const int kof = kt * 64;
#pragma unroll
        for (int t = 0; t < 2; ++t) {
            const int r = t * 64 + srow;
            load_lds16(Ag + (size_t)r * K_DIM + kof + scol,
                       &A_lds[sb][(t * 64 + wave * 16) * 64]);
            load_lds16(Bg + (size_t)r * K_DIM + kof + scol,
                       &B_lds[sb][(t * 64 + wave * 16) * 64]);
        }
    };

    auto COMPUTE = [&](int cb) {
        int4v a[2][2], b[2][2];  // [ks][tile]
#pragma unroll
        for (int ks = 0; ks < 2; ++ks)
#pragma unroll
            for (int ti = 0; ti < 2; ++ti) {
                const int ch = ((((ks << 1) | hi) ^ rswz) << 4);
                a[ks][ti] = *(const int4v*)
                    &A_lds[cb][(waveM * 64 + ti * 32 + l31) * 64 + ch];
                b[ks][ti] = *(const int4v*)
                    &B_lds[cb][(waveN * 64 + ti * 32 + l31) * 64 + ch];
            }
#pragma unroll
        for (int ks = 0; ks < 2; ++ks)
#pragma unroll
            for (int mi = 0; mi < 2; ++mi)
#pragma unroll
                for (int ni = 0; ni < 2; ++ni)
                    acc[mi][ni] = __builtin_amdgcn_mfma_i32_32x32x32_i8(
                        a[ks][mi], b[ks][ni], acc[mi][ni], 0, 0, 0);
    };

    // ---- prologue: tiles 0,1 in flight ----
    STAGE(0, 0);
    STAGE(1, 1);

    // ---- main loop: steady-state 12 outstanding after STAGE; vmcnt(8)
    // completes tile t only -- t+1/t+2 loads stay in flight across barriers.
    int cb = 0;  // t % 3
    for (int t = 0; t < NT - 2; ++t) {
        const int sb = (cb == 0) ? 2 : cb - 1;  // (t+2) % 3
        STAGE(sb, t + 2);
        asm volatile("s_waitcnt vmcnt(8)" ::: "memory");
        __builtin_amdgcn_s_barrier();
        __builtin_amdgcn_sched_barrier(0);   // keep ds_reads below the barrier
        COMPUTE(cb);
        asm volatile("s_waitcnt lgkmcnt(0)" ::: "memory");
        __builtin_amdgcn_sched_barrier(0);   // keep MFMAs/reads above exit barrier
        __builtin_amdgcn_s_barrier();
        cb = (cb == 2) ? 0 : cb + 1;
    }

    // ---- tail: tile NT-2 (4 newer loads in flight), then NT-1 ----
    asm volatile("s_waitcnt vmcnt(4)" ::: "memory");
    __builtin_amdgcn_s_barrier();
    __builtin_amdgcn_sched_barrier(0);
    COMPUTE(cb);
    cb = (cb == 2) ? 0 : cb + 1;

    asm volatile("s_waitcnt vmcnt(0)" ::: "memory");
    __builtin_amdgcn_s_barrier();
    __builtin_amdgcn_sched_barrier(0);
    COMPUTE(cb);

    // epilogue: + b_q, rescale, rint, clip, dequant.
    // 32x32 C/D: col = lane&31 (N), row_m = (reg&3) + 8*(reg>>2) + 4*hi.
    // Nontemporal stores: write-once stream must not evict A/B from L2/L3.
    const float s_in  = *in_scale_p;
    const float s_out = *out_scale_p;
    const float wscale = *gmax_p / QMAXF;
    const float bias_scale = s_in * wscale;
    const float ratio = bias_scale / s_out;

#pragma unroll
    for (int ni = 0; ni < 2; ++ni) {
        const int col = blockN0 + waveN * 64 + ni * 32 + l31;
        const int bq = (int)rintf(bias[col] / bias_scale);
#pragma unroll
        for (int mi = 0; mi < 2; ++mi) {
#pragma unroll
            for (int reg = 0; reg < 16; ++reg) {
                const int row = blockM0 + waveM * 64 + mi * 32 +
                                (reg & 3) + 8 * (reg >> 2) + 4 * hi;
                const int av = acc[mi][ni][reg] + bq;
                float f = rintf((float)av * ratio);
                f = fminf(fmaxf(f, -128.0f), 127.0f);
                __builtin_nontemporal_store(f * s_out, &out[(size_t)row * N_DIM + col]);
            }
        }
    }
}

extern "C" void kernel_launch(void* const* d_in, const int* in_sizes, int n_in,
                              void* d_out, int out_size, void* d_ws, size_t ws_size,
                              hipStream_t stream) {
    const float* x         = (const float*)d_in[0];
    const float* w         = (const float*)d_in[1];
    const float* bias      = (const float*)d_in[2];
    const float* in_scale  = (const float*)d_in[3];
    const float* out_scale = (const float*)d_in[4];
    float* out = (float*)d_out;

    unsigned char* ws = (unsigned char*)d_ws;
    float* partials = (float*)ws;                       // [PREP_GRID] f32
    float* gmax_p   = (float*)(ws + 8192);              // global |w| max
    signed char* xq  = (signed char*)(ws + 8448);
    signed char* wTq = xq + (size_t)M_DIM * K_DIM;

    // A: quantx + w-absmax partials (independent work, one BW pass, no sync)
    quantx_wmax_kernel<<<PREP_GRID, 256, 0, stream>>>(
        x, xq, in_scale, w, partials, M_DIM * K_DIM / 16, K_DIM * N_DIM / 4);

    // B: reduce partials -> wscale; quantize+transpose w; write gmax for gemm
    dim3 wgrid(N_DIM / 64, K_DIM / 64);  // (100, 25)
    quantw_kernel<<<wgrid, 256, 0, stream>>>(w, wTq, partials, gmax_p, PREP_GRID);

    gemm_i8_kernel<<<3200, 256, 0, stream>>>(xq, wTq, bias, gmax_p,
                                             in_scale, out_scale, out);
}